// Round 1
// baseline (365.852 us; speedup 1.0000x reference)
//
#include <hip/hip_runtime.h>
#include <hip/hip_bf16.h>

// ---------------------------------------------------------------------------
// HybridFusionNetworkWithUncertainty — MI355X (gfx950)
// Pipeline: 4x intra GEMM(+relu) -> LN -> q/v GEMM -> attn(4x4) -> W1 GEMM(+ps fixup) -> fc+sigmoid
// All GEMMs: bf16 MFMA 16x16x32, fp32 accumulate. NT layout (weights are [N][K] row-major).
// ws layout (needs ~112 MiB):
//   [0,64MiB)    h (65536x512 bf16)   -> reused by q (32MiB) + v (32MiB)
//   [64,128MiB)  H (65536x512 bf16)   -> reused by z (32MiB) + out f32 (16MiB)
// ---------------------------------------------------------------------------

typedef __bf16 bf16;
typedef __bf16 bf16x4_t __attribute__((ext_vector_type(4)));
typedef __bf16 bf16x8_t __attribute__((ext_vector_type(8)));
typedef float  f32x4_t  __attribute__((ext_vector_type(4)));

__device__ __forceinline__ bf16x8_t cvt_f32x8_bf16(f32x4_t a, f32x4_t b) {
  bf16x8_t r;
  r[0] = (bf16)a[0]; r[1] = (bf16)a[1]; r[2] = (bf16)a[2]; r[3] = (bf16)a[3];
  r[4] = (bf16)b[0]; r[5] = (bf16)b[1]; r[6] = (bf16)b[2]; r[7] = (bf16)b[3];
  return r;
}

// C[M,N] = act(A[M,K] * W[N,ldw]^T + bias [+ ps*Wtail]) ; BM=BN=128, BK=32, 256 thr
template<int A_IS_F32, int RELU, int OUT_BF16, int PS_FIX>
__global__ __launch_bounds__(256)
void gemm_nt(const void* __restrict__ Av, const float* __restrict__ W, int ldw,
             const float* __restrict__ bias, void* __restrict__ Cv, int ldc,
             int K, const float* __restrict__ ps)
{
  const int tid  = threadIdx.x;
  const int lane = tid & 63;
  const int wid  = tid >> 6;
  const int wm   = wid >> 1, wn = wid & 1;      // 2x2 wave grid, 64x64 per wave
  const int row0 = blockIdx.y * 128, col0 = blockIdx.x * 128;

  __shared__ bf16 As[128][40];   // +8 pad: row stride 80B, 16B-aligned, ~2-way banks
  __shared__ bf16 Bs[128][40];

  f32x4_t acc[4][4];
#pragma unroll
  for (int i = 0; i < 4; ++i)
#pragma unroll
    for (int j = 0; j < 4; ++j) acc[i][j] = (f32x4_t){0.f, 0.f, 0.f, 0.f};

  const int srow  = tid >> 1;        // staging: 2 thr/row, 16 elems each
  const int skoff = (tid & 1) * 16;
  const int fr    = lane & 15;
  const int koff  = (lane >> 4) * 8; // 8 contiguous k per lane (bijection cancels A vs B)

  for (int k0 = 0; k0 < K; k0 += 32) {
    if (A_IS_F32) {
      const float* Ap = (const float*)Av + (size_t)(row0 + srow) * K + k0 + skoff;
      f32x4_t a0 = *(const f32x4_t*)(Ap + 0);
      f32x4_t a1 = *(const f32x4_t*)(Ap + 4);
      f32x4_t a2 = *(const f32x4_t*)(Ap + 8);
      f32x4_t a3 = *(const f32x4_t*)(Ap + 12);
      *(bf16x8_t*)&As[srow][skoff]     = cvt_f32x8_bf16(a0, a1);
      *(bf16x8_t*)&As[srow][skoff + 8] = cvt_f32x8_bf16(a2, a3);
    } else {
      const bf16* Ap = (const bf16*)Av + (size_t)(row0 + srow) * K + k0 + skoff;
      *(bf16x8_t*)&As[srow][skoff]     = *(const bf16x8_t*)(Ap);
      *(bf16x8_t*)&As[srow][skoff + 8] = *(const bf16x8_t*)(Ap + 8);
    }
    {
      const float* Wp = W + (size_t)(col0 + srow) * ldw + k0 + skoff;
      f32x4_t b0 = *(const f32x4_t*)(Wp + 0);
      f32x4_t b1 = *(const f32x4_t*)(Wp + 4);
      f32x4_t b2 = *(const f32x4_t*)(Wp + 8);
      f32x4_t b3 = *(const f32x4_t*)(Wp + 12);
      *(bf16x8_t*)&Bs[srow][skoff]     = cvt_f32x8_bf16(b0, b1);
      *(bf16x8_t*)&Bs[srow][skoff + 8] = cvt_f32x8_bf16(b2, b3);
    }
    __syncthreads();

    bf16x8_t ar[4], br[4];
#pragma unroll
    for (int mi = 0; mi < 4; ++mi) ar[mi] = *(const bf16x8_t*)&As[wm * 64 + mi * 16 + fr][koff];
#pragma unroll
    for (int ni = 0; ni < 4; ++ni) br[ni] = *(const bf16x8_t*)&Bs[wn * 64 + ni * 16 + fr][koff];
#pragma unroll
    for (int mi = 0; mi < 4; ++mi)
#pragma unroll
      for (int ni = 0; ni < 4; ++ni)
        acc[mi][ni] = __builtin_amdgcn_mfma_f32_16x16x32_bf16(ar[mi], br[ni], acc[mi][ni], 0, 0, 0);
    __syncthreads();
  }

  // epilogue: row = row0+wm*64+mi*16+4*(lane>>4)+j ; col = col0+wn*64+ni*16+(lane&15)
  const int rb = row0 + wm * 64 + 4 * (lane >> 4);
  const int cb = col0 + wn * 64 + fr;
  float bv[4], wt[4][4];
#pragma unroll
  for (int ni = 0; ni < 4; ++ni) bv[ni] = bias[cb + ni * 16];
  if (PS_FIX) {
#pragma unroll
    for (int ni = 0; ni < 4; ++ni)
#pragma unroll
      for (int m = 0; m < 4; ++m) wt[ni][m] = W[(size_t)(cb + ni * 16) * ldw + K + m];
  }
#pragma unroll
  for (int mi = 0; mi < 4; ++mi) {
#pragma unroll
    for (int j = 0; j < 4; ++j) {
      const int r = rb + mi * 16 + j;
      f32x4_t psv = (f32x4_t){0.f, 0.f, 0.f, 0.f};
      if (PS_FIX) psv = *(const f32x4_t*)(ps + (size_t)r * 4);
#pragma unroll
      for (int ni = 0; ni < 4; ++ni) {
        float val = acc[mi][ni][j] + bv[ni];
        if (PS_FIX)
          val += psv[0] * wt[ni][0] + psv[1] * wt[ni][1] + psv[2] * wt[ni][2] + psv[3] * wt[ni][3];
        if (RELU) val = fmaxf(val, 0.f);
        const int c = cb + ni * 16;
        if (OUT_BF16) ((bf16*)Cv)[(size_t)r * ldc + c] = (bf16)val;
        else          ((float*)Cv)[(size_t)r * ldc + c] = val;
      }
    }
  }
}

// LayerNorm over rows of 512 (bf16 in -> bf16 out), one wave per row
__global__ __launch_bounds__(256)
void ln_kernel(const bf16* __restrict__ h, bf16* __restrict__ Ho,
               const float* __restrict__ g, const float* __restrict__ bta)
{
  const int row  = blockIdx.x * 4 + (threadIdx.x >> 6);
  const int lane = threadIdx.x & 63;
  const bf16x8_t x = *(const bf16x8_t*)(h + (size_t)row * 512 + lane * 8);
  float xf[8]; float s = 0.f, s2 = 0.f;
#pragma unroll
  for (int j = 0; j < 8; ++j) { xf[j] = (float)x[j]; s += xf[j]; s2 += xf[j] * xf[j]; }
#pragma unroll
  for (int off = 1; off < 64; off <<= 1) { s += __shfl_xor(s, off); s2 += __shfl_xor(s2, off); }
  const float mu  = s * (1.f / 512.f);
  const float var = s2 * (1.f / 512.f) - mu * mu;
  const float inv = rsqrtf(var + 1e-5f);
  f32x4_t g0 = *(const f32x4_t*)(g + lane * 8);
  f32x4_t g1 = *(const f32x4_t*)(g + lane * 8 + 4);
  f32x4_t b0 = *(const f32x4_t*)(bta + lane * 8);
  f32x4_t b1 = *(const f32x4_t*)(bta + lane * 8 + 4);
  bf16x8_t o;
#pragma unroll
  for (int j = 0; j < 4; ++j) o[j]     = (bf16)((xf[j] - mu) * inv * g0[j] + b0[j]);
#pragma unroll
  for (int j = 0; j < 4; ++j) o[4 + j] = (bf16)((xf[4 + j] - mu) * inv * g1[j] + b1[j]);
  *(bf16x8_t*)(Ho + (size_t)row * 512 + lane * 8) = o;
}

// attention: per batch row b, 4x4 scores (k=q per source bug), softmax(-UW*(vi+vj)), z = s@v
__global__ __launch_bounds__(256)
void attn_kernel(const bf16* __restrict__ q, const bf16* __restrict__ v,
                 const float* __restrict__ pvars, bf16* __restrict__ z)
{
  const int b    = blockIdx.x * 4 + (threadIdx.x >> 6);
  const int lane = threadIdx.x & 63;
  float qf[4][4], vf[4][4];
#pragma unroll
  for (int i = 0; i < 4; ++i) {
    bf16x4_t qq = *(const bf16x4_t*)(q + ((size_t)b * 4 + i) * 256 + lane * 4);
    bf16x4_t vv = *(const bf16x4_t*)(v + ((size_t)b * 4 + i) * 256 + lane * 4);
#pragma unroll
    for (int c = 0; c < 4; ++c) { qf[i][c] = (float)qq[c]; vf[i][c] = (float)vv[c]; }
  }
  float s[4][4];
#pragma unroll
  for (int i = 0; i < 4; ++i)
#pragma unroll
    for (int j = 0; j < 4; ++j)
      s[i][j] = qf[i][0] * qf[j][0] + qf[i][1] * qf[j][1] + qf[i][2] * qf[j][2] + qf[i][3] * qf[j][3];
#pragma unroll
  for (int off = 1; off < 64; off <<= 1)
#pragma unroll
    for (int i = 0; i < 4; ++i)
#pragma unroll
      for (int j = 0; j < 4; ++j) s[i][j] += __shfl_xor(s[i][j], off);

  float var4[4];
#pragma unroll
  for (int m = 0; m < 4; ++m) var4[m] = pvars[(size_t)b * 4 + m];
  float w[4][4];
#pragma unroll
  for (int i = 0; i < 4; ++i) {
    float t[4]; float mx = -1e30f;
#pragma unroll
    for (int j = 0; j < 4; ++j) { t[j] = s[i][j] - 0.1f * (var4[i] + var4[j]); mx = fmaxf(mx, t[j]); }
    float sum = 0.f;
#pragma unroll
    for (int j = 0; j < 4; ++j) { t[j] = expf(t[j] - mx); sum += t[j]; }
    const float is = 1.f / sum;
#pragma unroll
    for (int j = 0; j < 4; ++j) w[i][j] = t[j] * is;
  }
#pragma unroll
  for (int i = 0; i < 4; ++i) {
    bf16x4_t zo;
#pragma unroll
    for (int c = 0; c < 4; ++c) {
      float zf = w[i][0] * vf[0][c] + w[i][1] * vf[1][c] + w[i][2] * vf[2][c] + w[i][3] * vf[3][c];
      zo[c] = (bf16)zf;
    }
    *(bf16x4_t*)(z + ((size_t)b * 4 + i) * 256 + lane * 4) = zo;
  }
}

// final fc (256 -> 1) + sigmoid, one wave per row
__global__ __launch_bounds__(256)
void fc_kernel(const float* __restrict__ o, const float* __restrict__ wfc,
               const float* __restrict__ bfc, float* __restrict__ out)
{
  const int b    = blockIdx.x * 4 + (threadIdx.x >> 6);
  const int lane = threadIdx.x & 63;
  f32x4_t ov = *(const f32x4_t*)(o + (size_t)b * 256 + lane * 4);
  f32x4_t wv = *(const f32x4_t*)(wfc + lane * 4);
  float p = ov[0] * wv[0] + ov[1] * wv[1] + ov[2] * wv[2] + ov[3] * wv[3];
#pragma unroll
  for (int off = 1; off < 64; off <<= 1) p += __shfl_xor(p, off);
  if (lane == 0) {
    const float lg = p + bfc[0];
    out[b] = 1.f / (1.f + expf(-lg));
  }
}

extern "C" void kernel_launch(void* const* d_in, const int* in_sizes, int n_in,
                              void* d_out, int out_size, void* d_ws, size_t ws_size,
                              hipStream_t stream)
{
  (void)in_sizes; (void)n_in; (void)out_size; (void)ws_size;
  // setup_inputs() dict order: per model i: feat,W_intra,b_intra ; then
  // pred_scores, pred_vars, ln_g, ln_b, Wq,bq, Wk,bk, Wv,bv, W1,b1, Wfc,bfc
  const float* feat[4] = {(const float*)d_in[0], (const float*)d_in[3],
                          (const float*)d_in[6], (const float*)d_in[9]};
  const float* Wi[4]   = {(const float*)d_in[1], (const float*)d_in[4],
                          (const float*)d_in[7], (const float*)d_in[10]};
  const float* bi[4]   = {(const float*)d_in[2], (const float*)d_in[5],
                          (const float*)d_in[8], (const float*)d_in[11]};
  const int Kd[4] = {1024, 768, 512, 640};
  const float* ps  = (const float*)d_in[12];
  const float* pv  = (const float*)d_in[13];
  const float* lng = (const float*)d_in[14];
  const float* lnb = (const float*)d_in[15];
  const float* Wq  = (const float*)d_in[16];
  const float* bq  = (const float*)d_in[17];
  const float* Wv  = (const float*)d_in[20];
  const float* bvp = (const float*)d_in[21];
  const float* W1  = (const float*)d_in[22];
  const float* b1  = (const float*)d_in[23];
  const float* Wfc = (const float*)d_in[24];
  const float* bfc = (const float*)d_in[25];

  char* ws = (char*)d_ws;
  bf16*  hbuf = (bf16*)ws;                             // 64 MiB
  bf16*  Hbuf = (bf16*)(ws + 67108864);                // 64 MiB
  bf16*  qbuf = (bf16*)ws;                             // reuse h region
  bf16*  vbuf = (bf16*)(ws + 33554432);
  bf16*  zbuf = (bf16*)(ws + 67108864);                // reuse H region
  float* obuf = (float*)(ws + 67108864 + 33554432);    // 16 MiB

  // stage A: 4x intra GEMM + relu -> h[(b*4+i)*512 + n]  (bf16)
  for (int i = 0; i < 4; ++i) {
    dim3 g(512 / 128, 16384 / 128);
    hipLaunchKernelGGL((gemm_nt<1, 1, 1, 0>), g, dim3(256), 0, stream,
                       (const void*)feat[i], Wi[i], Kd[i], bi[i],
                       (void*)(hbuf + i * 512), 2048, Kd[i], nullptr);
  }
  // stage B: LayerNorm -> H
  hipLaunchKernelGGL(ln_kernel, dim3(65536 / 4), dim3(256), 0, stream, hbuf, Hbuf, lng, lnb);
  // stage C: q, v projections (65536 x 256, K=512)
  {
    dim3 g(256 / 128, 65536 / 128);
    hipLaunchKernelGGL((gemm_nt<0, 0, 1, 0>), g, dim3(256), 0, stream,
                       (const void*)Hbuf, Wq, 512, bq, (void*)qbuf, 256, 512, nullptr);
    hipLaunchKernelGGL((gemm_nt<0, 0, 1, 0>), g, dim3(256), 0, stream,
                       (const void*)Hbuf, Wv, 512, bvp, (void*)vbuf, 256, 512, nullptr);
  }
  // stage D: attention -> z (16384 x 1024)
  hipLaunchKernelGGL(attn_kernel, dim3(16384 / 4), dim3(256), 0, stream, qbuf, vbuf, pv, zbuf);
  // stage E: W1 GEMM (K=1024) + pred_scores rank-4 fixup (cols 1024..1027 of W1)
  {
    dim3 g(256 / 128, 16384 / 128);
    hipLaunchKernelGGL((gemm_nt<0, 0, 0, 1>), g, dim3(256), 0, stream,
                       (const void*)zbuf, W1, 1028, b1, (void*)obuf, 256, 1024, ps);
  }
  // stage F: fc + sigmoid -> d_out (16384 x 1 f32)
  hipLaunchKernelGGL(fc_kernel, dim3(16384 / 4), dim3(256), 0, stream, obuf, Wfc, bfc, (float*)d_out);
}

// Round 2
// 325.692 us; speedup vs baseline: 1.1233x; 1.1233x over previous
//
#include <hip/hip_runtime.h>
#include <hip/hip_bf16.h>

// ---------------------------------------------------------------------------
// HybridFusionNetworkWithUncertainty — MI355X (gfx950), round 2
// Changes vs r1: batched intra GEMM (1 dispatch, z=model), fused q||v dispatch,
// 2-phase register prefetch in the GEMM K-loop, bijective XCD-chunked swizzle.
// ws layout:
//   [0,64MiB)    h (65536x512 bf16)   -> reused by q (32MiB) + v (32MiB)
//   [64,128MiB)  H (65536x512 bf16)   -> reused by z (32MiB) + obuf f32 (16MiB)
// ---------------------------------------------------------------------------

typedef __bf16 bf16;
typedef __bf16 bf16x4_t __attribute__((ext_vector_type(4)));
typedef __bf16 bf16x8_t __attribute__((ext_vector_type(8)));
typedef float  f32x4_t  __attribute__((ext_vector_type(4)));

__device__ __forceinline__ bf16x8_t cvt8(f32x4_t a, f32x4_t b) {
  bf16x8_t r;
  r[0] = (bf16)a[0]; r[1] = (bf16)a[1]; r[2] = (bf16)a[2]; r[3] = (bf16)a[3];
  r[4] = (bf16)b[0]; r[5] = (bf16)b[1]; r[6] = (bf16)b[2]; r[7] = (bf16)b[3];
  return r;
}

// Core 128x128xBK32 MFMA GEMM with 2-phase register prefetch.
// A: [*, lda] f32 or bf16 rows at arow0..+127 ; W: [*, ldw] f32 rows at bcol0..+127.
template<int A_IS_F32>
__device__ __forceinline__ void gemm_core(
    const void* __restrict__ Av, int lda,
    const float* __restrict__ W, int ldw, int bcol0,
    int arow0, int K,
    bf16 (* __restrict__ As)[40], bf16 (* __restrict__ Bs)[40],
    f32x4_t acc[4][4])
{
  const int tid   = threadIdx.x;
  const int lane  = tid & 63;
  const int srow  = tid >> 1;        // staging: 2 thr/row, 16 elems each
  const int skoff = (tid & 1) * 16;
  const int fr    = lane & 15;
  const int koff  = (lane >> 4) * 8;
  const int wid   = tid >> 6;
  const int wm    = wid >> 1, wn = wid & 1;

  const float* Af = A_IS_F32 ? ((const float*)Av + (size_t)(arow0 + srow) * lda + skoff) : nullptr;
  const bf16*  Ah = A_IS_F32 ? nullptr : ((const bf16*)Av + (size_t)(arow0 + srow) * lda + skoff);
  const float* Bf = W + (size_t)(bcol0 + srow) * ldw + skoff;

  f32x4_t fa0, fa1, fa2, fa3;        // A prefetch (f32 path)
  bf16x8_t ha0, ha1;                 // A prefetch (bf16 path)
  f32x4_t fb0, fb1, fb2, fb3;        // B prefetch

  auto load_tile = [&](int k0) {
    if (A_IS_F32) {
      fa0 = *(const f32x4_t*)(Af + k0 + 0);
      fa1 = *(const f32x4_t*)(Af + k0 + 4);
      fa2 = *(const f32x4_t*)(Af + k0 + 8);
      fa3 = *(const f32x4_t*)(Af + k0 + 12);
    } else {
      ha0 = *(const bf16x8_t*)(Ah + k0);
      ha1 = *(const bf16x8_t*)(Ah + k0 + 8);
    }
    fb0 = *(const f32x4_t*)(Bf + k0 + 0);
    fb1 = *(const f32x4_t*)(Bf + k0 + 4);
    fb2 = *(const f32x4_t*)(Bf + k0 + 8);
    fb3 = *(const f32x4_t*)(Bf + k0 + 12);
  };

  load_tile(0);
  for (int k0 = 0; k0 < K; k0 += 32) {
    // commit staged tile to LDS (compiler inserts vmcnt wait here)
    if (A_IS_F32) {
      *(bf16x8_t*)&As[srow][skoff]     = cvt8(fa0, fa1);
      *(bf16x8_t*)&As[srow][skoff + 8] = cvt8(fa2, fa3);
    } else {
      *(bf16x8_t*)&As[srow][skoff]     = ha0;
      *(bf16x8_t*)&As[srow][skoff + 8] = ha1;
    }
    *(bf16x8_t*)&Bs[srow][skoff]     = cvt8(fb0, fb1);
    *(bf16x8_t*)&Bs[srow][skoff + 8] = cvt8(fb2, fb3);
    __syncthreads();                       // tile ready
    if (k0 + 32 < K) load_tile(k0 + 32);   // issue next loads; in flight over MFMA
    bf16x8_t ar[4], br[4];
#pragma unroll
    for (int mi = 0; mi < 4; ++mi) ar[mi] = *(const bf16x8_t*)&As[wm * 64 + mi * 16 + fr][koff];
#pragma unroll
    for (int ni = 0; ni < 4; ++ni) br[ni] = *(const bf16x8_t*)&Bs[wn * 64 + ni * 16 + fr][koff];
#pragma unroll
    for (int mi = 0; mi < 4; ++mi)
#pragma unroll
      for (int ni = 0; ni < 4; ++ni)
        acc[mi][ni] = __builtin_amdgcn_mfma_f32_16x16x32_bf16(ar[mi], br[ni], acc[mi][ni], 0, 0, 0);
    __syncthreads();                       // all waves done reading before overwrite
  }
}

// epilogue: local row = wm*64+mi*16+4*(lane>>4)+j ; local col = wn*64+ni*16+(lane&15)
template<int RELU>
__device__ __forceinline__ void epi_bf16(f32x4_t acc[4][4], bf16* __restrict__ C, int ldc,
                                         const float* __restrict__ bias)
{
  const int lane = threadIdx.x & 63;
  const int wid  = threadIdx.x >> 6;
  const int wm = wid >> 1, wn = wid & 1;
  const int fr = lane & 15;
  const int rb = wm * 64 + 4 * (lane >> 4);
  const int cb = wn * 64 + fr;
  float bv[4];
#pragma unroll
  for (int ni = 0; ni < 4; ++ni) bv[ni] = bias[cb + ni * 16];
#pragma unroll
  for (int mi = 0; mi < 4; ++mi)
#pragma unroll
    for (int j = 0; j < 4; ++j)
#pragma unroll
      for (int ni = 0; ni < 4; ++ni) {
        float val = acc[mi][ni][j] + bv[ni];
        if (RELU) val = fmaxf(val, 0.f);
        C[(size_t)(rb + mi * 16 + j) * ldc + cb + ni * 16] = (bf16)val;
      }
}

// ---- stage A: batched intra GEMM + relu -> h[(b*4+i)*512+n] (bf16) ----
__global__ __launch_bounds__(256) void intra_kernel(
    const float* __restrict__ f0, const float* __restrict__ Wt0, const float* __restrict__ bb0,
    const float* __restrict__ f1, const float* __restrict__ Wt1, const float* __restrict__ bb1,
    const float* __restrict__ f2, const float* __restrict__ Wt2, const float* __restrict__ bb2,
    const float* __restrict__ f3, const float* __restrict__ Wt3, const float* __restrict__ bb3,
    bf16* __restrict__ hbuf)
{
  __shared__ bf16 As[128][40];
  __shared__ bf16 Bs[128][40];
  const int bid = blockIdx.x;                 // 2048 blocks
  const int lid = (bid & 7) * 256 + (bid >> 3);  // XCD-chunked bijection
  const int x = lid & 3, y = (lid >> 2) & 127, z = lid >> 9;
  const float* fp; const float* Wp; const float* bp; int K;
  switch (z) {
    case 0:  fp = f0; Wp = Wt0; bp = bb0; K = 1024; break;
    case 1:  fp = f1; Wp = Wt1; bp = bb1; K = 768;  break;
    case 2:  fp = f2; Wp = Wt2; bp = bb2; K = 512;  break;
    default: fp = f3; Wp = Wt3; bp = bb3; K = 640;  break;
  }
  f32x4_t acc[4][4];
#pragma unroll
  for (int i = 0; i < 4; ++i)
#pragma unroll
    for (int j = 0; j < 4; ++j) acc[i][j] = (f32x4_t){0.f, 0.f, 0.f, 0.f};
  gemm_core<1>(fp, K, Wp, K, x * 128, y * 128, K, As, Bs, acc);
  bf16* C = hbuf + (size_t)(y * 128) * 2048 + z * 512 + x * 128;
  epi_bf16<1>(acc, C, 2048, bp + x * 128);
}

// ---- stage C: fused q||v projections (65536 x 256 each, K=512) ----
__global__ __launch_bounds__(256) void qv_kernel(
    const bf16* __restrict__ H,
    const float* __restrict__ Wq, const float* __restrict__ bq,
    const float* __restrict__ Wv, const float* __restrict__ bv,
    bf16* __restrict__ qbuf, bf16* __restrict__ vbuf)
{
  __shared__ bf16 As[128][40];
  __shared__ bf16 Bs[128][40];
  const int bid = blockIdx.x;                 // 2048 blocks
  const int lid = (bid & 7) * 256 + (bid >> 3);
  const int x = lid & 3, y = lid >> 2;        // y: 0..511
  const float* Wp = (x < 2) ? Wq : Wv;
  const float* bp = (x < 2) ? bq : bv;
  bf16* out = (x < 2) ? qbuf : vbuf;
  const int c0 = (x & 1) * 128;
  f32x4_t acc[4][4];
#pragma unroll
  for (int i = 0; i < 4; ++i)
#pragma unroll
    for (int j = 0; j < 4; ++j) acc[i][j] = (f32x4_t){0.f, 0.f, 0.f, 0.f};
  gemm_core<0>(H, 512, Wp, 512, c0, y * 128, 512, As, Bs, acc);
  epi_bf16<0>(acc, out + (size_t)(y * 128) * 256 + c0, 256, bp + c0);
}

// ---- stage E: W1 GEMM (K=1024) + pred_scores rank-4 fixup, f32 out ----
__global__ __launch_bounds__(256) void w1_kernel(
    const bf16* __restrict__ zb, const float* __restrict__ W1,
    const float* __restrict__ b1, const float* __restrict__ ps,
    float* __restrict__ obuf)
{
  __shared__ bf16 As[128][40];
  __shared__ bf16 Bs[128][40];
  const int bid = blockIdx.x;                 // 256 blocks
  const int lid = (bid & 7) * 32 + (bid >> 3);
  const int x = lid & 1, y = lid >> 1;        // y: 0..127
  f32x4_t acc[4][4];
#pragma unroll
  for (int i = 0; i < 4; ++i)
#pragma unroll
    for (int j = 0; j < 4; ++j) acc[i][j] = (f32x4_t){0.f, 0.f, 0.f, 0.f};
  gemm_core<0>(zb, 1024, W1, 1028, x * 128, y * 128, 1024, As, Bs, acc);

  const int lane = threadIdx.x & 63;
  const int wid  = threadIdx.x >> 6;
  const int wm = wid >> 1, wn = wid & 1;
  const int fr = lane & 15;
  const int rb = wm * 64 + 4 * (lane >> 4);
  const int cb = x * 128 + wn * 64 + fr;      // global col
  float bv[4], wt[4][4];
#pragma unroll
  for (int ni = 0; ni < 4; ++ni) {
    bv[ni] = b1[cb + ni * 16];
#pragma unroll
    for (int m = 0; m < 4; ++m) wt[ni][m] = W1[(size_t)(cb + ni * 16) * 1028 + 1024 + m];
  }
#pragma unroll
  for (int mi = 0; mi < 4; ++mi)
#pragma unroll
    for (int j = 0; j < 4; ++j) {
      const int r = y * 128 + rb + mi * 16 + j;      // global row
      f32x4_t psv = *(const f32x4_t*)(ps + (size_t)r * 4);
#pragma unroll
      for (int ni = 0; ni < 4; ++ni) {
        float val = acc[mi][ni][j] + bv[ni]
                  + psv[0] * wt[ni][0] + psv[1] * wt[ni][1]
                  + psv[2] * wt[ni][2] + psv[3] * wt[ni][3];
        obuf[(size_t)r * 256 + cb + ni * 16] = val;
      }
    }
}

// ---- LayerNorm over rows of 512 (bf16 -> bf16), one wave per row ----
__global__ __launch_bounds__(256)
void ln_kernel(const bf16* __restrict__ h, bf16* __restrict__ Ho,
               const float* __restrict__ g, const float* __restrict__ bta)
{
  const int row  = blockIdx.x * 4 + (threadIdx.x >> 6);
  const int lane = threadIdx.x & 63;
  const bf16x8_t x = *(const bf16x8_t*)(h + (size_t)row * 512 + lane * 8);
  float xf[8]; float s = 0.f, s2 = 0.f;
#pragma unroll
  for (int j = 0; j < 8; ++j) { xf[j] = (float)x[j]; s += xf[j]; s2 += xf[j] * xf[j]; }
#pragma unroll
  for (int off = 1; off < 64; off <<= 1) { s += __shfl_xor(s, off); s2 += __shfl_xor(s2, off); }
  const float mu  = s * (1.f / 512.f);
  const float var = s2 * (1.f / 512.f) - mu * mu;
  const float inv = rsqrtf(var + 1e-5f);
  f32x4_t g0 = *(const f32x4_t*)(g + lane * 8);
  f32x4_t g1 = *(const f32x4_t*)(g + lane * 8 + 4);
  f32x4_t b0 = *(const f32x4_t*)(bta + lane * 8);
  f32x4_t b1 = *(const f32x4_t*)(bta + lane * 8 + 4);
  bf16x8_t o;
#pragma unroll
  for (int j = 0; j < 4; ++j) o[j]     = (bf16)((xf[j] - mu) * inv * g0[j] + b0[j]);
#pragma unroll
  for (int j = 0; j < 4; ++j) o[4 + j] = (bf16)((xf[4 + j] - mu) * inv * g1[j] + b1[j]);
  *(bf16x8_t*)(Ho + (size_t)row * 512 + lane * 8) = o;
}

// ---- attention: per batch row, 4x4 scores (k=q), softmax(-UW*(vi+vj)), z=s@v ----
__global__ __launch_bounds__(256)
void attn_kernel(const bf16* __restrict__ q, const bf16* __restrict__ v,
                 const float* __restrict__ pvars, bf16* __restrict__ z)
{
  const int b    = blockIdx.x * 4 + (threadIdx.x >> 6);
  const int lane = threadIdx.x & 63;
  float qf[4][4], vf[4][4];
#pragma unroll
  for (int i = 0; i < 4; ++i) {
    bf16x4_t qq = *(const bf16x4_t*)(q + ((size_t)b * 4 + i) * 256 + lane * 4);
    bf16x4_t vv = *(const bf16x4_t*)(v + ((size_t)b * 4 + i) * 256 + lane * 4);
#pragma unroll
    for (int c = 0; c < 4; ++c) { qf[i][c] = (float)qq[c]; vf[i][c] = (float)vv[c]; }
  }
  float s[4][4];
#pragma unroll
  for (int i = 0; i < 4; ++i)
#pragma unroll
    for (int j = 0; j < 4; ++j)
      s[i][j] = qf[i][0] * qf[j][0] + qf[i][1] * qf[j][1] + qf[i][2] * qf[j][2] + qf[i][3] * qf[j][3];
#pragma unroll
  for (int off = 1; off < 64; off <<= 1)
#pragma unroll
    for (int i = 0; i < 4; ++i)
#pragma unroll
      for (int j = 0; j < 4; ++j) s[i][j] += __shfl_xor(s[i][j], off);

  float var4[4];
#pragma unroll
  for (int m = 0; m < 4; ++m) var4[m] = pvars[(size_t)b * 4 + m];
  float w[4][4];
#pragma unroll
  for (int i = 0; i < 4; ++i) {
    float t[4]; float mx = -1e30f;
#pragma unroll
    for (int j = 0; j < 4; ++j) { t[j] = s[i][j] - 0.1f * (var4[i] + var4[j]); mx = fmaxf(mx, t[j]); }
    float sum = 0.f;
#pragma unroll
    for (int j = 0; j < 4; ++j) { t[j] = expf(t[j] - mx); sum += t[j]; }
    const float is = 1.f / sum;
#pragma unroll
    for (int j = 0; j < 4; ++j) w[i][j] = t[j] * is;
  }
#pragma unroll
  for (int i = 0; i < 4; ++i) {
    bf16x4_t zo;
#pragma unroll
    for (int c = 0; c < 4; ++c) {
      float zf = w[i][0] * vf[0][c] + w[i][1] * vf[1][c] + w[i][2] * vf[2][c] + w[i][3] * vf[3][c];
      zo[c] = (bf16)zf;
    }
    *(bf16x4_t*)(z + ((size_t)b * 4 + i) * 256 + lane * 4) = zo;
  }
}

// ---- final fc (256 -> 1) + sigmoid ----
__global__ __launch_bounds__(256)
void fc_kernel(const float* __restrict__ o, const float* __restrict__ wfc,
               const float* __restrict__ bfc, float* __restrict__ out)
{
  const int b    = blockIdx.x * 4 + (threadIdx.x >> 6);
  const int lane = threadIdx.x & 63;
  f32x4_t ov = *(const f32x4_t*)(o + (size_t)b * 256 + lane * 4);
  f32x4_t wv = *(const f32x4_t*)(wfc + lane * 4);
  float p = ov[0] * wv[0] + ov[1] * wv[1] + ov[2] * wv[2] + ov[3] * wv[3];
#pragma unroll
  for (int off = 1; off < 64; off <<= 1) p += __shfl_xor(p, off);
  if (lane == 0) {
    const float lg = p + bfc[0];
    out[b] = 1.f / (1.f + expf(-lg));
  }
}

extern "C" void kernel_launch(void* const* d_in, const int* in_sizes, int n_in,
                              void* d_out, int out_size, void* d_ws, size_t ws_size,
                              hipStream_t stream)
{
  (void)in_sizes; (void)n_in; (void)out_size; (void)ws_size;
  const float* feat[4] = {(const float*)d_in[0], (const float*)d_in[3],
                          (const float*)d_in[6], (const float*)d_in[9]};
  const float* Wi[4]   = {(const float*)d_in[1], (const float*)d_in[4],
                          (const float*)d_in[7], (const float*)d_in[10]};
  const float* bi[4]   = {(const float*)d_in[2], (const float*)d_in[5],
                          (const float*)d_in[8], (const float*)d_in[11]};
  const float* ps  = (const float*)d_in[12];
  const float* pv  = (const float*)d_in[13];
  const float* lng = (const float*)d_in[14];
  const float* lnb = (const float*)d_in[15];
  const float* Wq  = (const float*)d_in[16];
  const float* bq  = (const float*)d_in[17];
  const float* Wv  = (const float*)d_in[20];
  const float* bvp = (const float*)d_in[21];
  const float* W1  = (const float*)d_in[22];
  const float* b1  = (const float*)d_in[23];
  const float* Wfc = (const float*)d_in[24];
  const float* bfc = (const float*)d_in[25];

  char* ws = (char*)d_ws;
  bf16*  hbuf = (bf16*)ws;                             // 64 MiB
  bf16*  Hbuf = (bf16*)(ws + 67108864);                // 64 MiB
  bf16*  qbuf = (bf16*)ws;                             // reuse h region
  bf16*  vbuf = (bf16*)(ws + 33554432);
  bf16*  zbuf = (bf16*)(ws + 67108864);                // reuse H region
  float* obuf = (float*)(ws + 67108864 + 33554432);    // 16 MiB

  // stage A: batched intra GEMM + relu (2048 blocks)
  hipLaunchKernelGGL(intra_kernel, dim3(2048), dim3(256), 0, stream,
                     feat[0], Wi[0], bi[0], feat[1], Wi[1], bi[1],
                     feat[2], Wi[2], bi[2], feat[3], Wi[3], bi[3], hbuf);
  // stage B: LayerNorm -> H
  hipLaunchKernelGGL(ln_kernel, dim3(65536 / 4), dim3(256), 0, stream, hbuf, Hbuf, lng, lnb);
  // stage C: fused q||v (2048 blocks)
  hipLaunchKernelGGL(qv_kernel, dim3(2048), dim3(256), 0, stream,
                     Hbuf, Wq, bq, Wv, bvp, qbuf, vbuf);
  // stage D: attention -> z
  hipLaunchKernelGGL(attn_kernel, dim3(16384 / 4), dim3(256), 0, stream, qbuf, vbuf, pv, zbuf);
  // stage E: W1 GEMM + ps fixup
  hipLaunchKernelGGL(w1_kernel, dim3(256), dim3(256), 0, stream, zbuf, W1, b1, ps, obuf);
  // stage F: fc + sigmoid
  hipLaunchKernelGGL(fc_kernel, dim3(16384 / 4), dim3(256), 0, stream, obuf, Wfc, bfc, (float*)d_out);
}

// Round 4
// 267.241 us; speedup vs baseline: 1.3690x; 1.2187x over previous
//
#include <hip/hip_runtime.h>
#include <hip/hip_bf16.h>

// ---------------------------------------------------------------------------
// HybridFusionNetworkWithUncertainty — MI355X (gfx950), round 4
// r3 bug: weights at [112M,117M) were clobbered by ln_kernel's H write
// ([64M,128M)). Fix: clobber-free layout within exactly 128 MiB:
//   [0,64M)   h ; LN in-place -> H ; after stage C reused: zbuf [0,32M),
//             obuf f32 [32M,48M)
//   [64M,128M) wb0-3 (2.875M, used only in stage A) ; then qvout (64M, stage C)
// qv/w1 convert their small f32 B-operands on the fly (reg-stage + prefetch);
// A operands (bf16 activations) use global_load_lds(16B) with source-side
// XOR swizzle (chunk c -> c ^ ((row>>1)&3)), matched by frag_read.
// ---------------------------------------------------------------------------

typedef __bf16 bf16;
typedef __bf16 bf16x4_t __attribute__((ext_vector_type(4)));
typedef __bf16 bf16x8_t __attribute__((ext_vector_type(8)));
typedef float  f32x4_t  __attribute__((ext_vector_type(4)));

__device__ __forceinline__ bf16x8_t cvt8(f32x4_t a, f32x4_t b) {
  bf16x8_t r;
  r[0] = (bf16)a[0]; r[1] = (bf16)a[1]; r[2] = (bf16)a[2]; r[3] = (bf16)a[3];
  r[4] = (bf16)b[0]; r[5] = (bf16)b[1]; r[6] = (bf16)b[2]; r[7] = (bf16)b[3];
  return r;
}

__device__ __forceinline__ void gl_lds16(const void* g, void* l) {
  __builtin_amdgcn_global_load_lds(
      (const __attribute__((address_space(1))) void*)g,
      (__attribute__((address_space(3))) void*)l, 16, 0, 0);
}

// LDS tile: linear [128 rows][32 bf16] = 8KB. Logical chunk c (8 bf16 = 16B)
// of row r lives at physical chunk c ^ ((r>>1)&3)  (XOR involution; <=2-way banks).
__device__ __forceinline__ bf16x8_t frag_read(const bf16* Ts, int row, int c0) {
  const int byte = row * 64 + ((c0 ^ ((row >> 1) & 3)) << 4);
  return *(const bf16x8_t*)((const char*)Ts + byte);
}

// DMA-stage a 128x32 bf16 tile: linear LDS dest (wave-uniform base + lane*16),
// swizzle applied on the per-lane GLOBAL source address (m173 pattern).
__device__ __forceinline__ void stage_dma(const bf16* __restrict__ src, int ld,
                                          int k0, bf16* lds) {
  const int l = threadIdx.x & 63;
  const int w = threadIdx.x >> 6;
#pragma unroll
  for (int j = 0; j < 2; ++j) {
    const int r  = w * 32 + j * 16 + (l >> 2);
    const int sc = (l & 3) ^ ((r >> 1) & 3);
    gl_lds16(src + (size_t)r * ld + k0 + sc * 8, (char*)lds + (w * 32 + j * 16) * 64);
  }
}

// MFMA step: 4x4 16x16x32 fragments per wave (2x2 wave grid, 64x64 each)
__device__ __forceinline__ void mfma_step(const bf16* As, const bf16* Bs,
                                          f32x4_t acc[4][4]) {
  const int lane = threadIdx.x & 63;
  const int wid  = threadIdx.x >> 6;
  const int wm = wid >> 1, wn = wid & 1;
  const int fr = lane & 15, c0 = lane >> 4;
  bf16x8_t ar[4], br[4];
#pragma unroll
  for (int mi = 0; mi < 4; ++mi) ar[mi] = frag_read(As, wm * 64 + mi * 16 + fr, c0);
#pragma unroll
  for (int ni = 0; ni < 4; ++ni) br[ni] = frag_read(Bs, wn * 64 + ni * 16 + fr, c0);
#pragma unroll
  for (int mi = 0; mi < 4; ++mi)
#pragma unroll
    for (int ni = 0; ni < 4; ++ni)
      acc[mi][ni] = __builtin_amdgcn_mfma_f32_16x16x32_bf16(ar[mi], br[ni], acc[mi][ni], 0, 0, 0);
}

// epilogue: local row = wm*64+mi*16+4*(lane>>4)+j ; local col = wn*64+ni*16+(lane&15)
template<int RELU>
__device__ __forceinline__ void epi_bf16(f32x4_t acc[4][4], bf16* __restrict__ C, int ldc,
                                         const float* __restrict__ bias) {
  const int lane = threadIdx.x & 63;
  const int wid  = threadIdx.x >> 6;
  const int wm = wid >> 1, wn = wid & 1;
  const int fr = lane & 15;
  const int rb = wm * 64 + 4 * (lane >> 4);
  const int cb = wn * 64 + fr;
  float bv[4];
#pragma unroll
  for (int ni = 0; ni < 4; ++ni) bv[ni] = bias[cb + ni * 16];
#pragma unroll
  for (int mi = 0; mi < 4; ++mi)
#pragma unroll
    for (int j = 0; j < 4; ++j)
#pragma unroll
      for (int ni = 0; ni < 4; ++ni) {
        float val = acc[mi][ni][j] + bv[ni];
        if (RELU) val = fmaxf(val, 0.f);
        C[(size_t)(rb + mi * 16 + j) * ldc + cb + ni * 16] = (bf16)val;
      }
}

// ---- prep: convert intra weights f32 -> bf16 (row-major copies) ----
__device__ __forceinline__ void cp8(bf16* d, const float* s) {
  f32x4_t x0 = *(const f32x4_t*)s;
  f32x4_t x1 = *(const f32x4_t*)(s + 4);
  *(bf16x8_t*)d = cvt8(x0, x1);
}

__global__ __launch_bounds__(256) void prep_kernel(
    const float* __restrict__ w0, const float* __restrict__ w1s,
    const float* __restrict__ w2, const float* __restrict__ w3,
    bf16* __restrict__ o0, bf16* __restrict__ o1,
    bf16* __restrict__ o2, bf16* __restrict__ o3) {
  const int t = blockIdx.x * 256 + threadIdx.x;   // 736 blocks = 188416 threads
  if (t < 65536)       { size_t i = (size_t)t * 8;            cp8(o0 + i, w0 + i); }
  else if (t < 114688) { size_t i = (size_t)(t - 65536) * 8;  cp8(o1 + i, w1s + i); }
  else if (t < 147456) { size_t i = (size_t)(t - 114688) * 8; cp8(o2 + i, w2 + i); }
  else                 { size_t i = (size_t)(t - 147456) * 8; cp8(o3 + i, w3 + i); }
}

// ---- stage A: batched intra GEMM + relu -> h[(b*4+z)*512+n] (bf16) ----
// A (feat f32) reg-staged with prefetch + swizzled ds_write ; B (bf16) DMA
__global__ __launch_bounds__(256) void intra_kernel(
    const float* __restrict__ f0, const float* __restrict__ f1,
    const float* __restrict__ f2, const float* __restrict__ f3,
    const bf16* __restrict__ wb0, const bf16* __restrict__ wb1,
    const bf16* __restrict__ wb2, const bf16* __restrict__ wb3,
    const float* __restrict__ bb0, const float* __restrict__ bb1,
    const float* __restrict__ bb2, const float* __restrict__ bb3,
    bf16* __restrict__ hbuf) {
  __shared__ bf16 As[128 * 32];
  __shared__ bf16 Bs[128 * 32];
  const int bid = blockIdx.x;                     // 2048 blocks
  const int lid = (bid & 7) * 256 + (bid >> 3);   // XCD-chunked bijection
  const int x = lid & 3;                          // N-block (col0 = x*128)
  const int g = lid >> 2;
  const int z = g & 3;                            // model (cycles fast -> balanced)
  const int y = g >> 2;                           // M-block (0..127)
  const float* fp; const bf16* wp; const float* bp; int K;
  switch (z) {
    case 0:  fp = f0; wp = wb0; bp = bb0; K = 1024; break;
    case 1:  fp = f1; wp = wb1; bp = bb1; K = 768;  break;
    case 2:  fp = f2; wp = wb2; bp = bb2; K = 512;  break;
    default: fp = f3; wp = wb3; bp = bb3; K = 640;  break;
  }
  const int tid   = threadIdx.x;
  const int srow  = tid >> 1;
  const int shalf = tid & 1;
  const float* Af = fp + (size_t)(y * 128 + srow) * K + shalf * 16;
  const bf16*  Bb = wp + (size_t)(x * 128) * K;

  f32x4_t acc[4][4];
#pragma unroll
  for (int i = 0; i < 4; ++i)
#pragma unroll
    for (int j = 0; j < 4; ++j) acc[i][j] = (f32x4_t){0.f, 0.f, 0.f, 0.f};

  f32x4_t a0, a1, a2, a3;
  a0 = *(const f32x4_t*)(Af + 0);  a1 = *(const f32x4_t*)(Af + 4);
  a2 = *(const f32x4_t*)(Af + 8);  a3 = *(const f32x4_t*)(Af + 12);

  const int sw = (srow >> 1) & 3;                 // write swizzle (matches frag_read)
  bf16* wA0 = (bf16*)((char*)As + srow * 64 + (((shalf * 2)    ) ^ sw) * 16);
  bf16* wA1 = (bf16*)((char*)As + srow * 64 + (((shalf * 2 + 1)) ^ sw) * 16);

  for (int k0 = 0; k0 < K; k0 += 32) {
    stage_dma(Bb, K, k0, Bs);                     // B DMA in flight
    *(bf16x8_t*)wA0 = cvt8(a0, a1);               // commit prefetched A
    *(bf16x8_t*)wA1 = cvt8(a2, a3);
    __syncthreads();
    if (k0 + 32 < K) {                            // next A loads fly over MFMA
      a0 = *(const f32x4_t*)(Af + k0 + 32);
      a1 = *(const f32x4_t*)(Af + k0 + 36);
      a2 = *(const f32x4_t*)(Af + k0 + 40);
      a3 = *(const f32x4_t*)(Af + k0 + 44);
    }
    mfma_step(As, Bs, acc);
    __syncthreads();
  }
  bf16* C = hbuf + (size_t)(y * 128) * 2048 + z * 512 + x * 128;
  epi_bf16<1>(acc, C, 2048, bp + x * 128);
}

// ---- stage C: fused q||v projection (65536 x 512, K=512) ----
// A (H bf16) DMA ; B (Wq/Wv f32) reg-staged with prefetch
__global__ __launch_bounds__(256) void qv_kernel(
    const bf16* __restrict__ H, const float* __restrict__ Wq,
    const float* __restrict__ Wv, const float* __restrict__ bq,
    const float* __restrict__ bv, bf16* __restrict__ qvout) {
  __shared__ bf16 As[128 * 32];
  __shared__ bf16 Bs[128 * 32];
  const int bid = blockIdx.x;                     // 2048 blocks
  const int lid = (bid & 7) * 256 + (bid >> 3);
  const int x = lid & 3, y = lid >> 2;            // y: 0..511
  const float* Wsrc = (x < 2) ? Wq : Wv;
  const int tid   = threadIdx.x;
  const int srow  = tid >> 1;
  const int shalf = tid & 1;
  const float* Bf = Wsrc + (size_t)((x & 1) * 128 + srow) * 512 + shalf * 16;
  const bf16*  Ab = H + (size_t)(y * 128) * 512;

  f32x4_t acc[4][4];
#pragma unroll
  for (int i = 0; i < 4; ++i)
#pragma unroll
    for (int j = 0; j < 4; ++j) acc[i][j] = (f32x4_t){0.f, 0.f, 0.f, 0.f};

  f32x4_t b0, b1, b2, b3;
  b0 = *(const f32x4_t*)(Bf + 0);  b1 = *(const f32x4_t*)(Bf + 4);
  b2 = *(const f32x4_t*)(Bf + 8);  b3 = *(const f32x4_t*)(Bf + 12);

  const int sw = (srow >> 1) & 3;
  bf16* wB0 = (bf16*)((char*)Bs + srow * 64 + (((shalf * 2)    ) ^ sw) * 16);
  bf16* wB1 = (bf16*)((char*)Bs + srow * 64 + (((shalf * 2 + 1)) ^ sw) * 16);

  for (int k0 = 0; k0 < 512; k0 += 32) {
    stage_dma(Ab, 512, k0, As);                   // A DMA in flight
    *(bf16x8_t*)wB0 = cvt8(b0, b1);               // commit prefetched B
    *(bf16x8_t*)wB1 = cvt8(b2, b3);
    __syncthreads();
    if (k0 + 32 < 512) {
      b0 = *(const f32x4_t*)(Bf + k0 + 32);
      b1 = *(const f32x4_t*)(Bf + k0 + 36);
      b2 = *(const f32x4_t*)(Bf + k0 + 40);
      b3 = *(const f32x4_t*)(Bf + k0 + 44);
    }
    mfma_step(As, Bs, acc);
    __syncthreads();
  }
  const float* bias = (x < 2) ? bq + x * 128 : bv + (x - 2) * 128;
  epi_bf16<0>(acc, qvout + (size_t)(y * 128) * 512 + x * 128, 512, bias);
}

// ---- stage E: W1 GEMM (K=1024, ldw=1028) + pred_scores rank-4 fixup ----
// A (z bf16) DMA ; B (W1 f32) reg-staged with prefetch
__global__ __launch_bounds__(256) void w1_kernel(
    const bf16* __restrict__ zb, const float* __restrict__ W1,
    const float* __restrict__ b1, const float* __restrict__ ps,
    float* __restrict__ obuf) {
  __shared__ bf16 As[128 * 32];
  __shared__ bf16 Bs[128 * 32];
  const int bid = blockIdx.x;                     // 256 blocks
  const int lid = (bid & 7) * 32 + (bid >> 3);
  const int x = lid & 1, y = lid >> 1;            // y: 0..127
  const int tid   = threadIdx.x;
  const int srow  = tid >> 1;
  const int shalf = tid & 1;
  const float* Bf = W1 + (size_t)(x * 128 + srow) * 1028 + shalf * 16;
  const bf16*  Ab = zb + (size_t)(y * 128) * 1024;

  f32x4_t acc[4][4];
#pragma unroll
  for (int i = 0; i < 4; ++i)
#pragma unroll
    for (int j = 0; j < 4; ++j) acc[i][j] = (f32x4_t){0.f, 0.f, 0.f, 0.f};

  f32x4_t b0, b1v, b2, b3;
  b0  = *(const f32x4_t*)(Bf + 0);  b1v = *(const f32x4_t*)(Bf + 4);
  b2  = *(const f32x4_t*)(Bf + 8);  b3  = *(const f32x4_t*)(Bf + 12);

  const int sw = (srow >> 1) & 3;
  bf16* wB0 = (bf16*)((char*)Bs + srow * 64 + (((shalf * 2)    ) ^ sw) * 16);
  bf16* wB1 = (bf16*)((char*)Bs + srow * 64 + (((shalf * 2 + 1)) ^ sw) * 16);

  for (int k0 = 0; k0 < 1024; k0 += 32) {
    stage_dma(Ab, 1024, k0, As);
    *(bf16x8_t*)wB0 = cvt8(b0, b1v);
    *(bf16x8_t*)wB1 = cvt8(b2, b3);
    __syncthreads();
    if (k0 + 32 < 1024) {
      b0  = *(const f32x4_t*)(Bf + k0 + 32);
      b1v = *(const f32x4_t*)(Bf + k0 + 36);
      b2  = *(const f32x4_t*)(Bf + k0 + 40);
      b3  = *(const f32x4_t*)(Bf + k0 + 44);
    }
    mfma_step(As, Bs, acc);
    __syncthreads();
  }

  const int lane = threadIdx.x & 63;
  const int wid  = threadIdx.x >> 6;
  const int wm = wid >> 1, wn = wid & 1;
  const int fr = lane & 15;
  const int rb = wm * 64 + 4 * (lane >> 4);
  const int cb = x * 128 + wn * 64 + fr;          // global col
  float bv[4], wt[4][4];
#pragma unroll
  for (int ni = 0; ni < 4; ++ni) {
    bv[ni] = b1[cb + ni * 16];
#pragma unroll
    for (int m = 0; m < 4; ++m) wt[ni][m] = W1[(size_t)(cb + ni * 16) * 1028 + 1024 + m];
  }
#pragma unroll
  for (int mi = 0; mi < 4; ++mi)
#pragma unroll
    for (int j = 0; j < 4; ++j) {
      const int r = y * 128 + rb + mi * 16 + j;   // global row
      f32x4_t psv = *(const f32x4_t*)(ps + (size_t)r * 4);
#pragma unroll
      for (int ni = 0; ni < 4; ++ni) {
        float val = acc[mi][ni][j] + bv[ni]
                  + psv[0] * wt[ni][0] + psv[1] * wt[ni][1]
                  + psv[2] * wt[ni][2] + psv[3] * wt[ni][3];
        obuf[(size_t)r * 256 + cb + ni * 16] = val;
      }
    }
}

// ---- LayerNorm over rows of 512, IN-PLACE (bf16), one wave per row ----
__global__ __launch_bounds__(256)
void ln_kernel(bf16* __restrict__ h, const float* __restrict__ g,
               const float* __restrict__ bta) {
  const int row  = blockIdx.x * 4 + (threadIdx.x >> 6);
  const int lane = threadIdx.x & 63;
  bf16* p = h + (size_t)row * 512 + lane * 8;
  const bf16x8_t x = *(const bf16x8_t*)p;
  float xf[8]; float s = 0.f, s2 = 0.f;
#pragma unroll
  for (int j = 0; j < 8; ++j) { xf[j] = (float)x[j]; s += xf[j]; s2 += xf[j] * xf[j]; }
#pragma unroll
  for (int off = 1; off < 64; off <<= 1) { s += __shfl_xor(s, off); s2 += __shfl_xor(s2, off); }
  const float mu  = s * (1.f / 512.f);
  const float var = s2 * (1.f / 512.f) - mu * mu;
  const float inv = rsqrtf(var + 1e-5f);
  f32x4_t g0 = *(const f32x4_t*)(g + lane * 8);
  f32x4_t g1 = *(const f32x4_t*)(g + lane * 8 + 4);
  f32x4_t b0 = *(const f32x4_t*)(bta + lane * 8);
  f32x4_t b1 = *(const f32x4_t*)(bta + lane * 8 + 4);
  bf16x8_t o;
#pragma unroll
  for (int j = 0; j < 4; ++j) o[j]     = (bf16)((xf[j] - mu) * inv * g0[j] + b0[j]);
#pragma unroll
  for (int j = 0; j < 4; ++j) o[4 + j] = (bf16)((xf[4 + j] - mu) * inv * g1[j] + b1[j]);
  *(bf16x8_t*)p = o;
}

// ---- attention: 4x4 scores (k=q per source bug), softmax(-UW*(vi+vj)), z=s@v ----
__global__ __launch_bounds__(256)
void attn_kernel(const bf16* __restrict__ qv, const float* __restrict__ pvars,
                 bf16* __restrict__ z) {
  const int b    = blockIdx.x * 4 + (threadIdx.x >> 6);
  const int lane = threadIdx.x & 63;
  float qf[4][4], vf[4][4];
#pragma unroll
  for (int i = 0; i < 4; ++i) {
    const bf16* row = qv + ((size_t)b * 4 + i) * 512;
    bf16x4_t qq = *(const bf16x4_t*)(row + lane * 4);
    bf16x4_t vv = *(const bf16x4_t*)(row + 256 + lane * 4);
#pragma unroll
    for (int c = 0; c < 4; ++c) { qf[i][c] = (float)qq[c]; vf[i][c] = (float)vv[c]; }
  }
  float s[4][4];
#pragma unroll
  for (int i = 0; i < 4; ++i)
#pragma unroll
    for (int j = 0; j < 4; ++j)
      s[i][j] = qf[i][0] * qf[j][0] + qf[i][1] * qf[j][1] + qf[i][2] * qf[j][2] + qf[i][3] * qf[j][3];
#pragma unroll
  for (int off = 1; off < 64; off <<= 1)
#pragma unroll
    for (int i = 0; i < 4; ++i)
#pragma unroll
      for (int j = 0; j < 4; ++j) s[i][j] += __shfl_xor(s[i][j], off);

  float var4[4];
#pragma unroll
  for (int m = 0; m < 4; ++m) var4[m] = pvars[(size_t)b * 4 + m];
  float w[4][4];
#pragma unroll
  for (int i = 0; i < 4; ++i) {
    float t[4]; float mx = -1e30f;
#pragma unroll
    for (int j = 0; j < 4; ++j) { t[j] = s[i][j] - 0.1f * (var4[i] + var4[j]); mx = fmaxf(mx, t[j]); }
    float sum = 0.f;
#pragma unroll
    for (int j = 0; j < 4; ++j) { t[j] = expf(t[j] - mx); sum += t[j]; }
    const float is = 1.f / sum;
#pragma unroll
    for (int j = 0; j < 4; ++j) w[i][j] = t[j] * is;
  }
#pragma unroll
  for (int i = 0; i < 4; ++i) {
    bf16x4_t zo;
#pragma unroll
    for (int c = 0; c < 4; ++c) {
      float zf = w[i][0] * vf[0][c] + w[i][1] * vf[1][c] + w[i][2] * vf[2][c] + w[i][3] * vf[3][c];
      zo[c] = (bf16)zf;
    }
    *(bf16x4_t*)(z + ((size_t)b * 4 + i) * 256 + lane * 4) = zo;
  }
}

// ---- final fc (256 -> 1) + sigmoid ----
__global__ __launch_bounds__(256)
void fc_kernel(const float* __restrict__ o, const float* __restrict__ wfc,
               const float* __restrict__ bfc, float* __restrict__ out) {
  const int b    = blockIdx.x * 4 + (threadIdx.x >> 6);
  const int lane = threadIdx.x & 63;
  f32x4_t ov = *(const f32x4_t*)(o + (size_t)b * 256 + lane * 4);
  f32x4_t wv = *(const f32x4_t*)(wfc + lane * 4);
  float p = ov[0] * wv[0] + ov[1] * wv[1] + ov[2] * wv[2] + ov[3] * wv[3];
#pragma unroll
  for (int off = 1; off < 64; off <<= 1) p += __shfl_xor(p, off);
  if (lane == 0) {
    const float lg = p + bfc[0];
    out[b] = 1.f / (1.f + expf(-lg));
  }
}

extern "C" void kernel_launch(void* const* d_in, const int* in_sizes, int n_in,
                              void* d_out, int out_size, void* d_ws, size_t ws_size,
                              hipStream_t stream) {
  (void)in_sizes; (void)n_in; (void)out_size; (void)ws_size;
  const float* feat[4] = {(const float*)d_in[0], (const float*)d_in[3],
                          (const float*)d_in[6], (const float*)d_in[9]};
  const float* Wi[4]   = {(const float*)d_in[1], (const float*)d_in[4],
                          (const float*)d_in[7], (const float*)d_in[10]};
  const float* bi[4]   = {(const float*)d_in[2], (const float*)d_in[5],
                          (const float*)d_in[8], (const float*)d_in[11]};
  const float* ps  = (const float*)d_in[12];
  const float* pv  = (const float*)d_in[13];
  const float* lng = (const float*)d_in[14];
  const float* lnb = (const float*)d_in[15];
  const float* Wq  = (const float*)d_in[16];
  const float* bq  = (const float*)d_in[17];
  const float* Wv  = (const float*)d_in[20];
  const float* bvp = (const float*)d_in[21];
  const float* W1  = (const float*)d_in[22];
  const float* b1  = (const float*)d_in[23];
  const float* Wfc = (const float*)d_in[24];
  const float* bfc = (const float*)d_in[25];

  char* ws = (char*)d_ws;
  const size_t MB = 1024 * 1024;
  // timeline-safe layout (128 MiB total):
  bf16*  hbuf  = (bf16*)ws;                        // [0,64M): h; LN in-place -> H
  bf16*  zbuf  = (bf16*)ws;                        // [0,32M): z  (after stage C)
  float* obuf  = (float*)(ws + 32 * MB);           // [32M,48M): W1 out (stage E)
  bf16*  wb0   = (bf16*)(ws + 64 * MB);            // [64M,65M)      stage A only
  bf16*  wb1   = (bf16*)(ws + 65 * MB);            // [65M,65.75M)
  bf16*  wb2   = (bf16*)(ws + 65 * MB + 786432);   // [65.75M,66.25M)
  bf16*  wb3   = (bf16*)(ws + 66 * MB + 262144);   // [66.25M,66.875M)
  bf16*  qvout = (bf16*)(ws + 64 * MB);            // [64M,128M): stage C (clobbers wb*)

  // stage 0: intra weights -> bf16
  hipLaunchKernelGGL(prep_kernel, dim3(736), dim3(256), 0, stream,
                     Wi[0], Wi[1], Wi[2], Wi[3], wb0, wb1, wb2, wb3);
  // stage A: batched intra GEMM + relu -> h
  hipLaunchKernelGGL(intra_kernel, dim3(2048), dim3(256), 0, stream,
                     feat[0], feat[1], feat[2], feat[3],
                     wb0, wb1, wb2, wb3, bi[0], bi[1], bi[2], bi[3], hbuf);
  // stage B: LayerNorm in-place
  hipLaunchKernelGGL(ln_kernel, dim3(65536 / 4), dim3(256), 0, stream, hbuf, lng, lnb);
  // stage C: fused q||v GEMM -> qvout
  hipLaunchKernelGGL(qv_kernel, dim3(2048), dim3(256), 0, stream,
                     hbuf, Wq, Wv, bq, bvp, qvout);
  // stage D: attention -> z
  hipLaunchKernelGGL(attn_kernel, dim3(16384 / 4), dim3(256), 0, stream, qvout, pv, zbuf);
  // stage E: W1 GEMM + ps fixup -> obuf
  hipLaunchKernelGGL(w1_kernel, dim3(256), dim3(256), 0, stream, zbuf, W1, b1, ps, obuf);
  // stage F: fc + sigmoid -> d_out
  hipLaunchKernelGGL(fc_kernel, dim3(16384 / 4), dim3(256), 0, stream, obuf, Wfc, bfc, (float*)d_out);
}